// Round 2
// baseline (689.857 us; speedup 1.0000x reference)
//
#include <hip/hip_runtime.h>
#include <cstdint>
#include <cstddef>

// Problem constants (fixed by reference shapes)
#define T_    4
#define B_    2
#define NW_   64
#define WS_   128
#define C_    256
#define NC3   768
#define H_    8
#define HD_   32
#define TOPK_ 4

// Workspace byte offsets (all 16B aligned). Total ~135.4 MB.
#define OFF_REGION 0u
#define OFF_PART   131072u
#define OFF_IDX    655360u
#define OFF_KCS    657408u
#define OFF_Q8     1181696u
#define OFF_K8     17958912u
#define OFF_V8     34736128u
#define OFF_KV     51513344u
#define OFF_ATTN   68290560u

// g = (t*B_+b)*NW_ + n, s in [0,128): float index of x[t,b,lt,lh,lw,0]
__device__ __forceinline__ int xoff_row(int g, int s) {
    int tb = g >> 6;               // t*2+b
    int n  = g & 63;
    int iwt = n >> 4, iwh = (n >> 2) & 3, iww = n & 3;
    int ipt = s >> 6, iph = (s >> 3) & 7, ipw = s & 7;
    int lt = iwt * 2 + ipt, lh = iwh * 8 + iph, lw = iww * 8 + ipw;
    return (((tb * 8 + lt) * 32 + lh) * 32 + lw) * 256;
}

// ---- K1a: per-(t,b,n) partial sum over s ----
__global__ __launch_bounds__(256) void k_partial(const float* __restrict__ x,
                                                 float* __restrict__ part) {
    int g = blockIdx.x;            // 512
    int c = threadIdx.x;
    float acc = 0.f;
    for (int s = 0; s < WS_; ++s) acc += x[xoff_row(g, s) + c];
    part[g * C_ + c] = acc;
}

// ---- K1b: region[b,n,c] = sum_t part / 128 ----
__global__ __launch_bounds__(256) void k_region(const float* __restrict__ part,
                                                float* __restrict__ region) {
    int bn = blockIdx.x;           // b*64+n, 128
    int c = threadIdx.x;
    int b = bn >> 6, n = bn & 63;
    float acc = 0.f;
    for (int t = 0; t < T_; ++t) acc += part[((t * 2 + b) * 64 + n) * C_ + c];
    region[bn * C_ + c] = acc * (1.0f / 128.0f);
}

// ---- K2: scores + top-4 (lowest-index tie-break, matching jax.lax.top_k) ----
__global__ __launch_bounds__(64) void k_scores(const float* __restrict__ region,
                                               int* __restrict__ idx) {
    int bi = blockIdx.x;           // b*64 + i, 128 blocks
    int b = bi >> 6, i = bi & 63;
    int tid = threadIdx.x;         // 0..63
    __shared__ float ri[C_];
    __shared__ float sc[64];
    for (int c = tid; c < C_; c += 64) ri[c] = region[(b * 64 + i) * C_ + c];
    __syncthreads();
    const float* rj = region + (size_t)(b * 64 + tid) * C_;
    float dot = 0.f;
    for (int c = 0; c < C_; ++c) dot += ri[c] * rj[c];
    sc[tid] = dot * 0.17677669529663687f;   // hd^-0.5 = 1/sqrt(32)
    __syncthreads();
    if (tid == 0) {
        for (int kk = 0; kk < TOPK_; ++kk) {
            float best = -INFINITY; int bj = 0;
            for (int j = 0; j < 64; ++j)
                if (sc[j] > best) { best = sc[j]; bj = j; }
            idx[bi * TOPK_ + kk] = bj;
            sc[bj] = -INFINITY;
        }
    }
}

// ---- K3: qkv GEMM (fp32) + bias + LIF spike -> q8/k8/v8 bytes ----
// BM=128, BN=64, BK=16, 256 threads, 8x4 micro-tile.
// Borderline elements (|v-2| < 1e-4) are re-decided with a serial
// ascending-k fp32 fused-FMA dot: this replicates BLAS sgemm's
// single-accumulator k-loop (K=256 < KC, no k-split), i.e. the numpy
// reference's own fp32 rounding — NOT the "true" fp64 value, which is
// MORE accurate than the ref and therefore flips spikes relative to it.
__global__ __launch_bounds__(256) void qkv_gemm(const float* __restrict__ x,
        const float* __restrict__ W, const float* __restrict__ bias,
        unsigned char* __restrict__ q8, unsigned char* __restrict__ k8,
        unsigned char* __restrict__ v8) {
    __shared__ float As[16][128];
    __shared__ float Bs[16][64];
    const int tid = threadIdx.x;
    const int mb = blockIdx.x;                 // 512 row tiles (= one (t,b,n))
    const int n0 = blockIdx.y * 64;            // 12 col tiles
    const int arow = tid >> 1;
    const int ak0 = (tid & 1) * 8;
    const float* aptr = x + xoff_row(mb, arow) + ak0;
    const int bk = tid >> 4;
    const int bn = (tid & 15) * 4;
    const float* bptr = W + (size_t)bk * NC3 + n0 + bn;
    const int tx = tid & 15, ty = tid >> 4;
    float acc[8][4];
#pragma unroll
    for (int i = 0; i < 8; ++i)
#pragma unroll
        for (int j = 0; j < 4; ++j) acc[i][j] = 0.f;

    for (int kt = 0; kt < 256; kt += 16) {
        float4 a0 = *(const float4*)(aptr + kt);
        float4 a1 = *(const float4*)(aptr + kt + 4);
        float4 bv = *(const float4*)(bptr + (size_t)kt * NC3);
        __syncthreads();
        As[ak0 + 0][arow] = a0.x; As[ak0 + 1][arow] = a0.y;
        As[ak0 + 2][arow] = a0.z; As[ak0 + 3][arow] = a0.w;
        As[ak0 + 4][arow] = a1.x; As[ak0 + 5][arow] = a1.y;
        As[ak0 + 6][arow] = a1.z; As[ak0 + 7][arow] = a1.w;
        *(float4*)&Bs[bk][bn] = bv;
        __syncthreads();
#pragma unroll
        for (int k = 0; k < 16; ++k) {
            float4 aa0 = *(const float4*)&As[k][ty * 8];
            float4 aa1 = *(const float4*)&As[k][ty * 8 + 4];
            float4 bb  = *(const float4*)&Bs[k][tx * 4];
            float av[8] = {aa0.x, aa0.y, aa0.z, aa0.w, aa1.x, aa1.y, aa1.z, aa1.w};
            float bw[4] = {bb.x, bb.y, bb.z, bb.w};
#pragma unroll
            for (int i = 0; i < 8; ++i)
#pragma unroll
                for (int j = 0; j < 4; ++j)
                    acc[i][j] = fmaf(av[i], bw[j], acc[i][j]);
        }
    }
    // epilogue: bias + spike(v >= 2), borderline rescue in serial fp32
    unsigned char* dst; int coff;
    if (n0 < 256)      { dst = q8; coff = n0; }
    else if (n0 < 512) { dst = k8; coff = n0 - 256; }
    else               { dst = v8; coff = n0 - 512; }
    float bj[4];
#pragma unroll
    for (int j = 0; j < 4; ++j) bj[j] = bias[n0 + tx * 4 + j];
#pragma unroll
    for (int i = 0; i < 8; ++i) {
        int srow = ty * 8 + i;
        int r = mb * 128 + srow;
        unsigned char sv[4];
#pragma unroll
        for (int j = 0; j < 4; ++j) {
            float v = acc[i][j] + bj[j];
            unsigned char s_;
            if (fabsf(v - 2.0f) < 1e-4f) {
                // borderline: replicate BLAS serial ascending-k fp32 FMA
                const float* ar = x + xoff_row(mb, srow);
                const float* wc = W + n0 + tx * 4 + j;
                float da = 0.f;
                for (int k = 0; k < 256; ++k)
                    da = fmaf(ar[k], wc[(size_t)k * NC3], da);
                da += bj[j];
                s_ = (da >= 2.0f) ? 1 : 0;
            } else {
                s_ = (v >= 2.0f) ? 1 : 0;
            }
            sv[j] = s_;
        }
        uchar4 sp; sp.x = sv[0]; sp.y = sv[1]; sp.z = sv[2]; sp.w = sv[3];
        *(uchar4*)(dst + (size_t)r * 256 + coff + tx * 4) = sp;
    }
}

// ---- K3.5: per-window column sums of k spikes (for ksum/D) ----
__global__ __launch_bounds__(256) void k_colsum(const unsigned char* __restrict__ k8,
                                                float* __restrict__ kcs) {
    int g = blockIdx.x;            // 512
    int c = threadIdx.x;
    int acc = 0;
    const unsigned char* p = k8 + (size_t)g * WS_ * C_ + c;
    for (int s = 0; s < WS_; ++s) acc += p[s * C_];
    kcs[g * C_ + c] = (float)acc;
}

// ---- K4: kv[g,h,d,e] = sum over 512 gathered rows of k[s,d]*v[s,e] (exact int) ----
__global__ __launch_bounds__(256) void kv_kernel(const unsigned char* __restrict__ k8,
        const unsigned char* __restrict__ v8, const int* __restrict__ idx,
        float* __restrict__ kvbuf) {
    int bid = blockIdx.x;          // 4096 = g*8 + h
    int g = bid >> 3, h = bid & 7;
    int tb = g >> 6, n = g & 63, b = tb & 1;
    int tid = threadIdx.x;
    __shared__ __align__(16) unsigned char klds[512 * 32];
    __shared__ __align__(16) unsigned char vlds[512 * 32];
    __shared__ int widx[TOPK_];
    if (tid < TOPK_) widx[tid] = idx[(b * 64 + n) * TOPK_ + tid];
    __syncthreads();
    int row = tid >> 1, half = tid & 1;
#pragma unroll
    for (int kk = 0; kk < TOPK_; ++kk) {
        int g2 = tb * 64 + widx[kk];
        size_t src = ((size_t)(g2 * 128 + row)) * 256 + h * 32 + half * 16;
        *(uint4*)&klds[(kk * 128 + row) * 32 + half * 16] = *(const uint4*)(k8 + src);
        *(uint4*)&vlds[(kk * 128 + row) * 32 + half * 16] = *(const uint4*)(v8 + src);
    }
    __syncthreads();
    int d = tid >> 3, eg = tid & 7;
    int acc0 = 0, acc1 = 0, acc2 = 0, acc3 = 0;
    for (int cc = 0; cc < 4; ++cc) {
        unsigned accp = 0;   // 4 packed byte-counters, <=128 each per chunk
        const unsigned char* kp = klds + cc * 128 * 32 + d;
        const unsigned char* vp = vlds + cc * 128 * 32 + eg * 4;
#pragma unroll 16
        for (int s = 0; s < 128; ++s) {
            unsigned kd = kp[s * 32];
            unsigned vw = *(const unsigned*)(vp + s * 32);
            accp += vw & (0u - kd);
        }
        acc0 += accp & 0xffu;         acc1 += (accp >> 8) & 0xffu;
        acc2 += (accp >> 16) & 0xffu; acc3 += (accp >> 24) & 0xffu;
    }
    float4 o = {(float)acc0, (float)acc1, (float)acc2, (float)acc3};
    *(float4*)&kvbuf[((size_t)(g * 8 + h) * 32 + d) * 32 + eg * 4] = o;
}

__device__ __forceinline__ unsigned p4(unsigned xv) {
    return (xv & 1u) | ((xv >> 7) & 2u) | ((xv >> 14) & 4u) | ((xv >> 21) & 8u);
}

// ---- K5: attn[g,s,c] = (q . kv[h,:,e]) / (q . ksum[h,:] + 1e-6) ----
// num/den are exact small integers in fp32 -> division is bitwise identical
// to the reference's fp32 division.
__global__ __launch_bounds__(256) void attn_kernel(const unsigned char* __restrict__ q8,
        const float* __restrict__ kvbuf, const float* __restrict__ kcs,
        const int* __restrict__ idx, float* __restrict__ attn) {
    int g = blockIdx.x;            // 512
    int tb = g >> 6, n = g & 63, b = tb & 1;
    int tid = threadIdx.x;
    int h = tid >> 5, e = tid & 31;
    __shared__ unsigned qb[128 * 8];
    __shared__ float kslds[C_];
    __shared__ int widx[TOPK_];
    if (tid < TOPK_) widx[tid] = idx[(b * 64 + n) * TOPK_ + tid];
    __syncthreads();
    float ks = 0.f;
#pragma unroll
    for (int kk = 0; kk < TOPK_; ++kk)
        ks += kcs[(size_t)(tb * 64 + widx[kk]) * C_ + tid];
    kslds[tid] = ks;
    // pack q spikes into per-(s,h) 32-bit masks
    for (int w = tid; w < 1024; w += 256) {
        int s = w >> 3, hh = w & 7;
        const uint4* p = (const uint4*)(q8 + ((size_t)(g * 128 + s)) * 256 + hh * 32);
        uint4 lo = p[0], hi = p[1];
        unsigned m = p4(lo.x) | (p4(lo.y) << 4) | (p4(lo.z) << 8) | (p4(lo.w) << 12)
                   | (p4(hi.x) << 16) | (p4(hi.y) << 20) | (p4(hi.z) << 24) | (p4(hi.w) << 28);
        qb[w] = m;
    }
    __syncthreads();
    float kvr[32], ksr[32];
#pragma unroll
    for (int d = 0; d < 32; ++d)
        kvr[d] = kvbuf[((size_t)(g * 8 + h) * 32 + d) * 32 + e];
#pragma unroll
    for (int d = 0; d < 32; ++d) ksr[d] = kslds[h * 32 + d];
    for (int s = 0; s < 128; ++s) {
        unsigned qw = qb[s * 8 + h];
        float r;
        if (qw == 0u) {
            r = 0.f;   // num=0, den=0 -> 0/(1e-6) = 0 exactly
        } else {
            float num = 0.f, den = 0.f;
#pragma unroll
            for (int d = 0; d < 32; ++d) {
                float m = (float)((qw >> d) & 1u);
                num = fmaf(m, kvr[d], num);
                den = fmaf(m, ksr[d], den);
            }
            r = num / (den + 1e-6f);
        }
        attn[((size_t)(g * 128 + s)) * 256 + tid] = r;
    }
}

// ---- K6: proj GEMM (fp32) + bias + un-windowize store ----
__global__ __launch_bounds__(256) void proj_gemm(const float* __restrict__ A,
        const float* __restrict__ W, const float* __restrict__ bias,
        float* __restrict__ out) {
    __shared__ float As[16][128];
    __shared__ float Bs[16][64];
    const int tid = threadIdx.x;
    const int mb = blockIdx.x;                 // 512
    const int n0 = blockIdx.y * 64;            // 4
    const int arow = tid >> 1;
    const int ak0 = (tid & 1) * 8;
    const float* aptr = A + ((size_t)(mb * 128 + arow)) * 256 + ak0;
    const int bk = tid >> 4;
    const int bn = (tid & 15) * 4;
    const float* bptr = W + (size_t)bk * 256 + n0 + bn;
    const int tx = tid & 15, ty = tid >> 4;
    float acc[8][4];
#pragma unroll
    for (int i = 0; i < 8; ++i)
#pragma unroll
        for (int j = 0; j < 4; ++j) acc[i][j] = 0.f;

    for (int kt = 0; kt < 256; kt += 16) {
        float4 a0 = *(const float4*)(aptr + kt);
        float4 a1 = *(const float4*)(aptr + kt + 4);
        float4 bv = *(const float4*)(bptr + (size_t)kt * 256);
        __syncthreads();
        As[ak0 + 0][arow] = a0.x; As[ak0 + 1][arow] = a0.y;
        As[ak0 + 2][arow] = a0.z; As[ak0 + 3][arow] = a0.w;
        As[ak0 + 4][arow] = a1.x; As[ak0 + 5][arow] = a1.y;
        As[ak0 + 6][arow] = a1.z; As[ak0 + 7][arow] = a1.w;
        *(float4*)&Bs[bk][bn] = bv;
        __syncthreads();
#pragma unroll
        for (int k = 0; k < 16; ++k) {
            float4 aa0 = *(const float4*)&As[k][ty * 8];
            float4 aa1 = *(const float4*)&As[k][ty * 8 + 4];
            float4 bb  = *(const float4*)&Bs[k][tx * 4];
            float av[8] = {aa0.x, aa0.y, aa0.z, aa0.w, aa1.x, aa1.y, aa1.z, aa1.w};
            float bw[4] = {bb.x, bb.y, bb.z, bb.w};
#pragma unroll
            for (int i = 0; i < 8; ++i)
#pragma unroll
                for (int j = 0; j < 4; ++j)
                    acc[i][j] = fmaf(av[i], bw[j], acc[i][j]);
        }
    }
    float bj[4];
#pragma unroll
    for (int j = 0; j < 4; ++j) bj[j] = bias[n0 + tx * 4 + j];
#pragma unroll
    for (int i = 0; i < 8; ++i) {
        int srow = ty * 8 + i;
        int off = xoff_row(mb, srow) + n0 + tx * 4;
        float4 o = {acc[i][0] + bj[0], acc[i][1] + bj[1],
                    acc[i][2] + bj[2], acc[i][3] + bj[3]};
        *(float4*)(out + off) = o;
    }
}

extern "C" void kernel_launch(void* const* d_in, const int* in_sizes, int n_in,
                              void* d_out, int out_size, void* d_ws, size_t ws_size,
                              hipStream_t stream) {
    (void)in_sizes; (void)n_in; (void)out_size; (void)ws_size;
    const float* x    = (const float*)d_in[0];
    const float* Wqkv = (const float*)d_in[1];
    const float* bqkv = (const float*)d_in[2];
    const float* Wp   = (const float*)d_in[3];
    const float* bp   = (const float*)d_in[4];
    char* ws = (char*)d_ws;
    float* region = (float*)(ws + OFF_REGION);
    float* part   = (float*)(ws + OFF_PART);
    int*   idxb   = (int*)  (ws + OFF_IDX);
    float* kcs    = (float*)(ws + OFF_KCS);
    unsigned char* q8 = (unsigned char*)(ws + OFF_Q8);
    unsigned char* k8 = (unsigned char*)(ws + OFF_K8);
    unsigned char* v8 = (unsigned char*)(ws + OFF_V8);
    float* kvbuf  = (float*)(ws + OFF_KV);
    float* attn   = (float*)(ws + OFF_ATTN);
    float* out    = (float*)d_out;

    k_partial  <<<512, 256, 0, stream>>>(x, part);
    k_region   <<<128, 256, 0, stream>>>(part, region);
    k_scores   <<<128,  64, 0, stream>>>(region, idxb);
    qkv_gemm   <<<dim3(512, 12), 256, 0, stream>>>(x, Wqkv, bqkv, q8, k8, v8);
    k_colsum   <<<512, 256, 0, stream>>>(k8, kcs);
    kv_kernel  <<<4096, 256, 0, stream>>>(k8, v8, idxb, kvbuf);
    attn_kernel<<<512, 256, 0, stream>>>(q8, kvbuf, kcs, idxb, attn);
    proj_gemm  <<<dim3(512, 4), 256, 0, stream>>>(attn, Wp, bp, out);
}

// Round 3
// 457.567 us; speedup vs baseline: 1.5077x; 1.5077x over previous
//
#include <hip/hip_runtime.h>
#include <cstdint>
#include <cstddef>

// Problem constants (fixed by reference shapes)
#define T_    4
#define B_    2
#define NW_   64
#define WS_   128
#define C_    256
#define NC3   768
#define H_    8
#define HD_   32
#define TOPK_ 4

// Workspace layout (bytes, all 16B aligned). Total ~107.6 MB.
// A2 doubles as A2p (proj input) after qkv_mfma has consumed it.
#define OFF_A2     0ull            // 512*128 rows x 512 bf16 (Ah|Al) = 67,108,864
#define OFF_BQ     67108864ull     // 768 x 768 bf16 ([n][k], k=[hi,hi,lo]) = 1,179,648
#define OFF_BP     68288512ull     // 256 x 768 bf16 = 393,216
#define OFF_Q8     68681728ull     // 512*128*256 bytes = 16,777,216
#define OFF_KB     85458944ull     // 512*256*4 u32 = 2,097,152
#define OFF_VB     87556096ull     // 2,097,152
#define OFF_KV     89653248ull     // 512*8*32*32 f32 = 16,777,216
#define OFF_KCS    106430464ull    // 512*256 f32 = 524,288
#define OFF_PART   106954752ull    // 524,288
#define OFF_REGION 107479040ull    // 131,072
#define OFF_IDX    107610112ull    // 2,048

typedef short short8 __attribute__((ext_vector_type(8)));
typedef float floatx4 __attribute__((ext_vector_type(4)));

__device__ __forceinline__ void gload16(const void* g, void* l) {
    __builtin_amdgcn_global_load_lds(
        (const __attribute__((address_space(1))) void*)g,
        (__attribute__((address_space(3))) void*)l, 16, 0, 0);
}

__device__ __forceinline__ short f2bf(float f) {
    unsigned u = __float_as_uint(f);
    unsigned r = (u + 0x7fffu + ((u >> 16) & 1u)) >> 16;
    return (short)r;
}
__device__ __forceinline__ float bf2f(short h) {
    return __uint_as_float(((unsigned)(unsigned short)h) << 16);
}

// g = (t*B_+b)*NW_ + n, s in [0,128): float index of x[t,b,lt,lh,lw,0]
__device__ __forceinline__ int xoff_row(int g, int s) {
    int tb = g >> 6;
    int n  = g & 63;
    int iwt = n >> 4, iwh = (n >> 2) & 3, iww = n & 3;
    int ipt = s >> 6, iph = (s >> 3) & 7, ipw = s & 7;
    int lt = iwt * 2 + ipt, lh = iwh * 8 + iph, lw = iww * 8 + ipw;
    return (((tb * 8 + lt) * 32 + lh) * 32 + lw) * 256;
}

// ---- K1a: per-(t,b,n) partial sum over s + write bf16 hi/lo split of x ----
__global__ __launch_bounds__(256) void k_partial_split(const float* __restrict__ x,
        float* __restrict__ part, short* __restrict__ A2) {
    int g = blockIdx.x;            // 512
    int c = threadIdx.x;
    float acc = 0.f;
    for (int s = 0; s < WS_; ++s) {
        float v = x[xoff_row(g, s) + c];
        acc += v;
        short hi = f2bf(v);
        short lo = f2bf(v - bf2f(hi));
        size_t row = (size_t)(g * 128 + s) * 512;
        A2[row + c] = hi;
        A2[row + 256 + c] = lo;
    }
    part[g * C_ + c] = acc;
}

// ---- K1b: region[b,n,c] = sum_t part / 128 ----
__global__ __launch_bounds__(256) void k_region(const float* __restrict__ part,
                                                float* __restrict__ region) {
    int bn = blockIdx.x;           // 128
    int c = threadIdx.x;
    int b = bn >> 6, n = bn & 63;
    float acc = 0.f;
    for (int t = 0; t < T_; ++t) acc += part[((t * 2 + b) * 64 + n) * C_ + c];
    region[bn * C_ + c] = acc * (1.0f / 128.0f);
}

// ---- K2: scores + top-4 (lowest-index tie-break) ----
__global__ __launch_bounds__(64) void k_scores(const float* __restrict__ region,
                                               int* __restrict__ idx) {
    int bi = blockIdx.x;           // 128
    int b = bi >> 6, i = bi & 63;
    int tid = threadIdx.x;
    __shared__ float ri[C_];
    __shared__ float sc[64];
    for (int c = tid; c < C_; c += 64) ri[c] = region[(b * 64 + i) * C_ + c];
    __syncthreads();
    const float* rj = region + (size_t)(b * 64 + tid) * C_;
    float dot = 0.f;
    for (int c = 0; c < C_; ++c) dot += ri[c] * rj[c];
    sc[tid] = dot * 0.17677669529663687f;
    __syncthreads();
    if (tid == 0) {
        for (int kk = 0; kk < TOPK_; ++kk) {
            float best = -INFINITY; int bj = 0;
            for (int j = 0; j < 64; ++j)
                if (sc[j] > best) { best = sc[j]; bj = j; }
            idx[bi * TOPK_ + kk] = bj;
            sc[bj] = -INFINITY;
        }
    }
}

// ---- B' builders: Bq[n][k] with k-rows [hi(W), hi(W), lo(W)] ----
__global__ __launch_bounds__(256) void b_build_qkv(const float* __restrict__ W,
                                                   short* __restrict__ Bq) {
    int k = blockIdx.x;                 // 0..767
    int n = blockIdx.y * 256 + threadIdx.x;  // 0..767
    float wv = W[(size_t)(k & 255) * NC3 + n];
    short hi = f2bf(wv);
    short out = (k < 512) ? hi : f2bf(wv - bf2f(hi));
    Bq[(size_t)n * 768 + k] = out;
}
__global__ __launch_bounds__(256) void b_build_proj(const float* __restrict__ W,
                                                    short* __restrict__ Bp) {
    int k = blockIdx.x;                 // 0..767
    int n = threadIdx.x;                // 0..255
    float wv = W[(size_t)(k & 255) * 256 + n];
    short hi = f2bf(wv);
    short out = (k < 512) ? hi : f2bf(wv - bf2f(hi));
    Bp[(size_t)n * 768 + k] = out;
}

// ---- K3: qkv GEMM via bf16x3 MFMA (K_eff=768) + spike + pack epilogue ----
// A2: [row][512] = [Ah(256)|Al(256)]; k-tile >=512 remaps back to Ah.
// by in [0,6): cols by*128..; by<2 -> q bytes, by in {2,3} -> k bits, {4,5} -> v bits.
__global__ __launch_bounds__(256) void qkv_mfma(const short* __restrict__ A2,
        const short* __restrict__ Bq, const float* __restrict__ x,
        const float* __restrict__ W, const float* __restrict__ bias,
        unsigned char* __restrict__ q8, unsigned* __restrict__ kb,
        unsigned* __restrict__ vb) {
    __shared__ __align__(16) char smem[16896];
    short* At = (short*)smem;            // [128][32]
    short* Bt = (short*)(smem + 8192);   // [128][32]
    const int tid = threadIdx.x;
    const int mb = blockIdx.x;           // 512 (= g)
    const int by = blockIdx.y;           // 6
    const int tq = tid >> 2, tr = tid & 3;
    const short* Arow0 = A2 + (size_t)(mb * 128 + tq) * 512 + tr * 8;
    const short* Arow1 = Arow0 + (size_t)64 * 512;
    const short* Brow0 = Bq + (size_t)(by * 128 + tq) * 768 + tr * 8;
    const short* Brow1 = Brow0 + (size_t)64 * 768;
    short* ldsA0 = At + tid * 8;  short* ldsA1 = At + 2048 + tid * 8;
    short* ldsB0 = Bt + tid * 8;  short* ldsB1 = Bt + 2048 + tid * 8;

    const int wv = tid >> 6, lane = tid & 63;
    const int m0 = (wv >> 1) * 64, n0w = (wv & 1) * 64;
    const int lm = lane & 15, lq = lane >> 4;

    floatx4 acc[4][4];
#pragma unroll
    for (int i = 0; i < 4; ++i)
#pragma unroll
        for (int j = 0; j < 4; ++j) acc[i][j] = (floatx4)0.f;

    for (int kt = 0; kt < 768; kt += 32) {
        int ca = (kt < 512) ? kt : kt - 512;
        __syncthreads();
        gload16(Arow0 + ca, ldsA0);
        gload16(Arow1 + ca, ldsA1);
        gload16(Brow0 + kt, ldsB0);
        gload16(Brow1 + kt, ldsB1);
        __syncthreads();
        short8 af[4], bf[4];
#pragma unroll
        for (int i = 0; i < 4; ++i)
            af[i] = *(const short8*)&At[(m0 + i * 16 + lm) * 32 + lq * 8];
#pragma unroll
        for (int j = 0; j < 4; ++j)
            bf[j] = *(const short8*)&Bt[(n0w + j * 16 + lm) * 32 + lq * 8];
#pragma unroll
        for (int i = 0; i < 4; ++i)
#pragma unroll
            for (int j = 0; j < 4; ++j)
                acc[i][j] = __builtin_amdgcn_mfma_f32_16x16x32_bf16(
                    af[i], bf[j], acc[i][j], 0, 0, 0);
    }

    // ---- epilogue: spike bytes into LDS (pitch 132 vs bank wall) ----
    __syncthreads();
    unsigned char* sp = (unsigned char*)smem;
#pragma unroll
    for (int i = 0; i < 4; ++i) {
#pragma unroll
        for (int j = 0; j < 4; ++j) {
            int cb = n0w + j * 16 + lm;          // col in block [0,128)
            int cg = by * 128 + cb;              // global col [0,768)
            float bj = bias[cg];
#pragma unroll
            for (int r = 0; r < 4; ++r) {
                int s = m0 + i * 16 + lq * 4 + r;
                float v = acc[i][j][r] + bj;
                unsigned char spk;
                if (fabsf(v - 2.0f) < 1e-4f) {
                    // borderline: replicate BLAS serial ascending-k fp32 FMA
                    const float* ar = x + xoff_row(mb, s);
                    const float* wc = W + cg;
                    float da = 0.f;
                    for (int k2 = 0; k2 < 256; ++k2)
                        da = fmaf(ar[k2], wc[(size_t)k2 * NC3], da);
                    da += bj;
                    spk = (da >= 2.0f) ? 1 : 0;
                } else {
                    spk = (v >= 2.0f) ? 1 : 0;
                }
                sp[s * 132 + cb] = spk;
            }
        }
    }
    __syncthreads();

    if (by < 2) {
        // q: copy bytes out vectorized. thread -> (row s, half)
        int s = tid >> 1, half = tid & 1;
        const unsigned* spw = (const unsigned*)sp;
        unsigned o[16];
#pragma unroll
        for (int i2 = 0; i2 < 16; ++i2) o[i2] = spw[s * 33 + half * 16 + i2];
        uint4* dst = (uint4*)(q8 + (size_t)(mb * 128 + s) * 256 + by * 128 + half * 64);
#pragma unroll
        for (int q4 = 0; q4 < 4; ++q4) {
            uint4 t4; t4.x = o[q4*4+0]; t4.y = o[q4*4+1]; t4.z = o[q4*4+2]; t4.w = o[q4*4+3];
            dst[q4] = t4;
        }
    } else {
        // k/v: bit-pack along s. thread -> (col j, s-half w2)
        int j = tid & 127, w2 = tid >> 7;
        unsigned m0w = 0, m1w = 0;
#pragma unroll
        for (int ii = 0; ii < 32; ++ii) {
            m0w |= (unsigned)(sp[(w2 * 64 + ii) * 132 + j] & 1) << ii;
            m1w |= (unsigned)(sp[(w2 * 64 + 32 + ii) * 132 + j] & 1) << ii;
        }
        int c = ((by - 2) & 1) * 128 + j;        // col within 256
        unsigned* dstb = ((by < 4) ? kb : vb) + ((size_t)mb * 256 + c) * 4 + w2 * 2;
        dstb[0] = m0w;
        dstb[1] = m1w;
    }
}

// ---- K3.5: column sums of k spikes from bitmasks ----
__global__ __launch_bounds__(256) void kcs_bits(const unsigned* __restrict__ kb,
                                                float* __restrict__ kcs) {
    int g = blockIdx.x;
    int c = threadIdx.x;
    const unsigned* p = kb + ((size_t)g * 256 + c) * 4;
    int acc = __popc(p[0]) + __popc(p[1]) + __popc(p[2]) + __popc(p[3]);
    kcs[g * C_ + c] = (float)acc;
}

// ---- K4: kv[g,h,d,e] = popcount over gathered s-bitmasks (exact int) ----
__global__ __launch_bounds__(256) void kv_bits(const unsigned* __restrict__ kb,
        const unsigned* __restrict__ vb, const int* __restrict__ idx,
        float* __restrict__ kvbuf) {
    int g = blockIdx.x;            // 512
    int tb = g >> 6, n = g & 63, b = tb & 1;
    int tid = threadIdx.x;
    __shared__ uint4 kbl[1024];    // [kk][256 c]
    __shared__ uint4 vbl[1024];
    __shared__ int widx[TOPK_];
    if (tid < TOPK_) widx[tid] = idx[(b * 64 + n) * TOPK_ + tid];
    __syncthreads();
#pragma unroll
    for (int kk = 0; kk < TOPK_; ++kk) {
        int g2 = tb * 64 + widx[kk];
        kbl[kk * 256 + tid] = *(const uint4*)&kb[((size_t)g2 * 256 + tid) * 4];
        vbl[kk * 256 + tid] = *(const uint4*)&vb[((size_t)g2 * 256 + tid) * 4];
    }
    __syncthreads();
    int h = tid >> 5, e = tid & 31;
    uint4 vw0 = vbl[0 * 256 + h * 32 + e];
    uint4 vw1 = vbl[1 * 256 + h * 32 + e];
    uint4 vw2 = vbl[2 * 256 + h * 32 + e];
    uint4 vw3 = vbl[3 * 256 + h * 32 + e];
    for (int d = 0; d < 32; ++d) {
        uint4 k0 = kbl[0 * 256 + h * 32 + d];
        uint4 k1 = kbl[1 * 256 + h * 32 + d];
        uint4 k2 = kbl[2 * 256 + h * 32 + d];
        uint4 k3 = kbl[3 * 256 + h * 32 + d];
        int acc = __popc(k0.x & vw0.x) + __popc(k0.y & vw0.y)
                + __popc(k0.z & vw0.z) + __popc(k0.w & vw0.w)
                + __popc(k1.x & vw1.x) + __popc(k1.y & vw1.y)
                + __popc(k1.z & vw1.z) + __popc(k1.w & vw1.w)
                + __popc(k2.x & vw2.x) + __popc(k2.y & vw2.y)
                + __popc(k2.z & vw2.z) + __popc(k2.w & vw2.w)
                + __popc(k3.x & vw3.x) + __popc(k3.y & vw3.y)
                + __popc(k3.z & vw3.z) + __popc(k3.w & vw3.w);
        kvbuf[((size_t)(g * 8 + h) * 32 + d) * 32 + e] = (float)acc;
    }
}

__device__ __forceinline__ unsigned p4(unsigned xv) {
    return (xv & 1u) | ((xv >> 7) & 2u) | ((xv >> 14) & 4u) | ((xv >> 21) & 8u);
}

// ---- K5: attn -> bf16 hi/lo directly into A2p (proj GEMM input) ----
__global__ __launch_bounds__(256) void attn_kernel(const unsigned char* __restrict__ q8,
        const float* __restrict__ kvbuf, const float* __restrict__ kcs,
        const int* __restrict__ idx, short* __restrict__ A2p) {
    int g = blockIdx.x;            // 512
    int tb = g >> 6, n = g & 63, b = tb & 1;
    int tid = threadIdx.x;
    int h = tid >> 5, e = tid & 31;
    __shared__ unsigned qb[128 * 8];
    __shared__ float kslds[C_];
    __shared__ int widx[TOPK_];
    if (tid < TOPK_) widx[tid] = idx[(b * 64 + n) * TOPK_ + tid];
    __syncthreads();
    float ks = 0.f;
#pragma unroll
    for (int kk = 0; kk < TOPK_; ++kk)
        ks += kcs[(size_t)(tb * 64 + widx[kk]) * C_ + tid];
    kslds[tid] = ks;
    for (int w = tid; w < 1024; w += 256) {
        int s = w >> 3, hh = w & 7;
        const uint4* p = (const uint4*)(q8 + ((size_t)(g * 128 + s)) * 256 + hh * 32);
        uint4 lo = p[0], hi = p[1];
        unsigned m = p4(lo.x) | (p4(lo.y) << 4) | (p4(lo.z) << 8) | (p4(lo.w) << 12)
                   | (p4(hi.x) << 16) | (p4(hi.y) << 20) | (p4(hi.z) << 24) | (p4(hi.w) << 28);
        qb[w] = m;
    }
    __syncthreads();
    float kvr[32], ksr[32];
#pragma unroll
    for (int d = 0; d < 32; ++d)
        kvr[d] = kvbuf[((size_t)(g * 8 + h) * 32 + d) * 32 + e];
#pragma unroll
    for (int d = 0; d < 32; ++d) ksr[d] = kslds[h * 32 + d];
    for (int s = 0; s < 128; ++s) {
        unsigned qw = qb[s * 8 + h];
        float r;
        if (qw == 0u) {
            r = 0.f;
        } else {
            float num = 0.f, den = 0.f;
#pragma unroll
            for (int d = 0; d < 32; ++d) {
                float m = (float)((qw >> d) & 1u);
                num = fmaf(m, kvr[d], num);
                den = fmaf(m, ksr[d], den);
            }
            r = num / (den + 1e-6f);
        }
        short hi16 = f2bf(r);
        short lo16 = f2bf(r - bf2f(hi16));
        size_t row = (size_t)(g * 128 + s) * 512;
        A2p[row + tid] = hi16;
        A2p[row + 256 + tid] = lo16;
    }
}

// ---- K6: proj GEMM via bf16x3 MFMA + bias + un-windowize store ----
__global__ __launch_bounds__(256) void proj_mfma(const short* __restrict__ A2p,
        const short* __restrict__ Bp, const float* __restrict__ bias,
        float* __restrict__ out) {
    __shared__ __align__(16) char smem[16384];
    short* At = (short*)smem;
    short* Bt = (short*)(smem + 8192);
    const int tid = threadIdx.x;
    const int mb = blockIdx.x;           // 512
    const int by = blockIdx.y;           // 2
    const int tq = tid >> 2, tr = tid & 3;
    const short* Arow0 = A2p + (size_t)(mb * 128 + tq) * 512 + tr * 8;
    const short* Arow1 = Arow0 + (size_t)64 * 512;
    const short* Brow0 = Bp + (size_t)(by * 128 + tq) * 768 + tr * 8;
    const short* Brow1 = Brow0 + (size_t)64 * 768;
    short* ldsA0 = At + tid * 8;  short* ldsA1 = At + 2048 + tid * 8;
    short* ldsB0 = Bt + tid * 8;  short* ldsB1 = Bt + 2048 + tid * 8;

    const int wv = tid >> 6, lane = tid & 63;
    const int m0 = (wv >> 1) * 64, n0w = (wv & 1) * 64;
    const int lm = lane & 15, lq = lane >> 4;

    floatx4 acc[4][4];
#pragma unroll
    for (int i = 0; i < 4; ++i)
#pragma unroll
        for (int j = 0; j < 4; ++j) acc[i][j] = (floatx4)0.f;

    for (int kt = 0; kt < 768; kt += 32) {
        int ca = (kt < 512) ? kt : kt - 512;
        __syncthreads();
        gload16(Arow0 + ca, ldsA0);
        gload16(Arow1 + ca, ldsA1);
        gload16(Brow0 + kt, ldsB0);
        gload16(Brow1 + kt, ldsB1);
        __syncthreads();
        short8 af[4], bf[4];
#pragma unroll
        for (int i = 0; i < 4; ++i)
            af[i] = *(const short8*)&At[(m0 + i * 16 + lm) * 32 + lq * 8];
#pragma unroll
        for (int j = 0; j < 4; ++j)
            bf[j] = *(const short8*)&Bt[(n0w + j * 16 + lm) * 32 + lq * 8];
#pragma unroll
        for (int i = 0; i < 4; ++i)
#pragma unroll
            for (int j = 0; j < 4; ++j)
                acc[i][j] = __builtin_amdgcn_mfma_f32_16x16x32_bf16(
                    af[i], bf[j], acc[i][j], 0, 0, 0);
    }

#pragma unroll
    for (int i = 0; i < 4; ++i) {
#pragma unroll
        for (int j = 0; j < 4; ++j) {
            int c = by * 128 + n0w + j * 16 + lm;    // out channel [0,256)
            float bj = bias[c];
#pragma unroll
            for (int r = 0; r < 4; ++r) {
                int s = m0 + i * 16 + lq * 4 + r;
                out[xoff_row(mb, s) + c] = acc[i][j][r] + bj;
            }
        }
    }
}

extern "C" void kernel_launch(void* const* d_in, const int* in_sizes, int n_in,
                              void* d_out, int out_size, void* d_ws, size_t ws_size,
                              hipStream_t stream) {
    (void)in_sizes; (void)n_in; (void)out_size; (void)ws_size;
    const float* x    = (const float*)d_in[0];
    const float* Wqkv = (const float*)d_in[1];
    const float* bqkv = (const float*)d_in[2];
    const float* Wp   = (const float*)d_in[3];
    const float* bp   = (const float*)d_in[4];
    char* ws = (char*)d_ws;
    short*    A2    = (short*)   (ws + OFF_A2);
    short*    Bq    = (short*)   (ws + OFF_BQ);
    short*    Bpj   = (short*)   (ws + OFF_BP);
    unsigned char* q8 = (unsigned char*)(ws + OFF_Q8);
    unsigned* kb    = (unsigned*)(ws + OFF_KB);
    unsigned* vb    = (unsigned*)(ws + OFF_VB);
    float*    kvbuf = (float*)   (ws + OFF_KV);
    float*    kcs   = (float*)   (ws + OFF_KCS);
    float*    part  = (float*)   (ws + OFF_PART);
    float*    region= (float*)   (ws + OFF_REGION);
    int*      idxb  = (int*)     (ws + OFF_IDX);
    float*    out   = (float*)d_out;

    b_build_qkv    <<<dim3(768, 3), 256, 0, stream>>>(Wqkv, Bq);
    b_build_proj   <<<768, 256, 0, stream>>>(Wp, Bpj);
    k_partial_split<<<512, 256, 0, stream>>>(x, part, A2);
    k_region       <<<128, 256, 0, stream>>>(part, region);
    k_scores       <<<128,  64, 0, stream>>>(region, idxb);
    qkv_mfma       <<<dim3(512, 6), 256, 0, stream>>>(A2, Bq, x, Wqkv, bqkv, q8, kb, vb);
    kcs_bits       <<<512, 256, 0, stream>>>(kb, kcs);
    kv_bits        <<<512, 256, 0, stream>>>(kb, vb, idxb, kvbuf);
    attn_kernel    <<<512, 256, 0, stream>>>(q8, kvbuf, kcs, idxb, A2);
    proj_mfma      <<<dim3(512, 2), 256, 0, stream>>>(A2, Bpj, bp, out);
}

// Round 4
// 450.377 us; speedup vs baseline: 1.5317x; 1.0160x over previous
//
#include <hip/hip_runtime.h>
#include <cstdint>
#include <cstddef>

// Problem constants (fixed by reference shapes)
#define T_    4
#define B_    2
#define NW_   64
#define WS_   128
#define C_    256
#define NC3   768
#define H_    8
#define HD_   32
#define TOPK_ 4
#define RCAP  65536

// Workspace layout (bytes, all 16B aligned). Total ~107.9 MB.
#define OFF_A2     0ull            // 65536 rows x 512 bf16 (octet-swizzled) = 67,108,864
#define OFF_BQ     67108864ull     // 768 x 768 bf16 [n][k'] swizzled = 1,179,648
#define OFF_BP     68288512ull     // 256 x 768 bf16 = 393,216
#define OFF_Q8     68681728ull     // 16,777,216
#define OFF_KB     85458944ull     // 2,097,152
#define OFF_VB     87556096ull     // 2,097,152
#define OFF_KV     89653248ull     // 16,777,216
#define OFF_KCS    106430464ull    // 524,288
#define OFF_PART   106954752ull    // 524,288
#define OFF_REGION 107479040ull    // 131,072
#define OFF_IDX    107610112ull    // 2,048
#define OFF_RL     107612160ull    // 262,144
#define OFF_RC     107874304ull    // 16

typedef short short8 __attribute__((ext_vector_type(8)));
typedef float floatx4 __attribute__((ext_vector_type(4)));

__device__ __forceinline__ void gload16(const void* g, void* l) {
    __builtin_amdgcn_global_load_lds(
        (const __attribute__((address_space(1))) void*)g,
        (__attribute__((address_space(3))) void*)l, 16, 0, 0);
}

__device__ __forceinline__ short f2bf(float f) {
    unsigned u = __float_as_uint(f);
    unsigned r = (u + 0x7fffu + ((u >> 16) & 1u)) >> 16;
    return (short)r;
}
__device__ __forceinline__ float bf2f(short h) {
    return __uint_as_float(((unsigned)(unsigned short)h) << 16);
}

// XOR-swizzle of 8-short octets within each aligned 8-octet (64-short) group.
// Applied at DRAM-write time so global_load_lds staging (lane-contiguous,
// unpaddable per m104) lands a layout whose fragment reads spread banks.
__device__ __forceinline__ int swz(int pos, int r) {
    int o = pos >> 3;
    int os = (o & ~7) | ((o ^ r) & 7);
    return (os << 3) | (pos & 7);
}

// g = (t*B_+b)*NW_ + n, s in [0,128): float index of x[t,b,lt,lh,lw,0]
__device__ __forceinline__ int xoff_row(int g, int s) {
    int tb = g >> 6;
    int n  = g & 63;
    int iwt = n >> 4, iwh = (n >> 2) & 3, iww = n & 3;
    int ipt = s >> 6, iph = (s >> 3) & 7, ipw = s & 7;
    int lt = iwt * 2 + ipt, lh = iwh * 8 + iph, lw = iww * 8 + ipw;
    return (((tb * 8 + lt) * 32 + lh) * 32 + lw) * 256;
}

// ---- K1a: per-(t,b,n) partial sum over s + write swizzled bf16 hi/lo split ----
__global__ __launch_bounds__(256) void k_partial_split(const float* __restrict__ x,
        float* __restrict__ part, short* __restrict__ A2) {
    int g = blockIdx.x;            // 512
    int c = threadIdx.x;
    float acc = 0.f;
    for (int s = 0; s < WS_; ++s) {
        float v = x[xoff_row(g, s) + c];
        acc += v;
        short hi = f2bf(v);
        short lo = f2bf(v - bf2f(hi));
        size_t row = (size_t)(g * 128 + s) * 512;
        A2[row + swz(c, s)] = hi;
        A2[row + swz(256 + c, s)] = lo;
    }
    part[g * C_ + c] = acc;
}

// ---- K1b: region[b,n,c] = sum_t part / 128 ----
__global__ __launch_bounds__(256) void k_region(const float* __restrict__ part,
                                                float* __restrict__ region) {
    int bn = blockIdx.x;           // 128
    int c = threadIdx.x;
    int b = bn >> 6, n = bn & 63;
    float acc = 0.f;
    for (int t = 0; t < T_; ++t) acc += part[((t * 2 + b) * 64 + n) * C_ + c];
    region[bn * C_ + c] = acc * (1.0f / 128.0f);
}

// ---- K2: scores + top-4 (lowest-index tie-break) ----
__global__ __launch_bounds__(64) void k_scores(const float* __restrict__ region,
                                               int* __restrict__ idx) {
    int bi = blockIdx.x;           // 128
    int b = bi >> 6, i = bi & 63;
    int tid = threadIdx.x;
    __shared__ float ri[C_];
    __shared__ float sc[64];
    for (int c = tid; c < C_; c += 64) ri[c] = region[(b * 64 + i) * C_ + c];
    __syncthreads();
    const float* rj = region + (size_t)(b * 64 + tid) * C_;
    float dot = 0.f;
    for (int c = 0; c < C_; ++c) dot += ri[c] * rj[c];
    sc[tid] = dot * 0.17677669529663687f;
    __syncthreads();
    if (tid == 0) {
        for (int kk = 0; kk < TOPK_; ++kk) {
            float best = -INFINITY; int bj = 0;
            for (int j = 0; j < 64; ++j)
                if (sc[j] > best) { best = sc[j]; bj = j; }
            idx[bi * TOPK_ + kk] = bj;
            sc[bj] = -INFINITY;
        }
    }
}

// ---- B' builders: Bq[n][k'] with k'-rows [hi(W), hi(W), lo(W)], swizzled ----
__global__ __launch_bounds__(256) void b_build_qkv(const float* __restrict__ W,
                                                   short* __restrict__ Bq) {
    int k = blockIdx.x;                      // 0..767
    int n = blockIdx.y * 256 + threadIdx.x;  // 0..767
    float wv = W[(size_t)(k & 255) * NC3 + n];
    short hi = f2bf(wv);
    short out = (k < 512) ? hi : f2bf(wv - bf2f(hi));
    Bq[(size_t)n * 768 + swz(k, n)] = out;
}
__global__ __launch_bounds__(256) void b_build_proj(const float* __restrict__ W,
                                                    short* __restrict__ Bp) {
    int k = blockIdx.x;                 // 0..767
    int n = threadIdx.x;                // 0..255
    float wv = W[(size_t)(k & 255) * 256 + n];
    short hi = f2bf(wv);
    short out = (k < 512) ? hi : f2bf(wv - bf2f(hi));
    Bp[(size_t)n * 768 + swz(k, n)] = out;
}

// ---- K3: qkv GEMM via bf16x3 MFMA (K_eff=768, BK=64) + spike/pack epilogue ----
// Borderline |v-2|<1e-4 recorded to rescue list; fixed by rescue_fix later.
__global__ __launch_bounds__(256) void qkv_mfma(const short* __restrict__ A2,
        const short* __restrict__ Bq, const float* __restrict__ bias,
        unsigned char* __restrict__ q8, unsigned* __restrict__ kb,
        unsigned* __restrict__ vb, unsigned* __restrict__ rl,
        unsigned* __restrict__ rcnt) {
    __shared__ __align__(16) char smem[32768];
    short* At = (short*)smem;            // [128][64]
    short* Bt = (short*)(smem + 16384);  // [128][64]
    const int tid = threadIdx.x;
    const int mb = blockIdx.x;           // 512 (= g)
    const int by = blockIdx.y;           // 6
    const int lr = tid >> 3, lc = (tid & 7) * 8;
    const short* Abase = A2 + (size_t)(mb * 128 + lr) * 512 + lc;
    const short* Bbase = Bq + (size_t)(by * 128 + lr) * 768 + lc;

    const int wv = tid >> 6, lane = tid & 63;
    const int m0 = (wv >> 1) * 64, n0w = (wv & 1) * 64;
    const int lm = lane & 15, lq = lane >> 4;
    const int sx = lm & 7;

    floatx4 acc[4][4];
#pragma unroll
    for (int i = 0; i < 4; ++i)
#pragma unroll
        for (int j = 0; j < 4; ++j) acc[i][j] = (floatx4)0.f;

    for (int kt = 0; kt < 768; kt += 64) {
        int ca = (kt < 512) ? kt : kt - 512;
        __syncthreads();
#pragma unroll
        for (int c = 0; c < 4; ++c) {
            gload16(Abase + ca + (size_t)c * 32 * 512, At + c * 2048 + tid * 8);
            gload16(Bbase + kt + (size_t)c * 32 * 768, Bt + c * 2048 + tid * 8);
        }
        __syncthreads();
#pragma unroll
        for (int kq = 0; kq < 2; ++kq) {
            short8 af[4], bfv[4];
            const int ko = ((kq * 4 + lq) ^ sx) * 8;
#pragma unroll
            for (int i = 0; i < 4; ++i)
                af[i] = *(const short8*)&At[(m0 + i * 16 + lm) * 64 + ko];
#pragma unroll
            for (int j = 0; j < 4; ++j)
                bfv[j] = *(const short8*)&Bt[(n0w + j * 16 + lm) * 64 + ko];
#pragma unroll
            for (int i = 0; i < 4; ++i)
#pragma unroll
                for (int j = 0; j < 4; ++j)
                    acc[i][j] = __builtin_amdgcn_mfma_f32_16x16x32_bf16(
                        af[i], bfv[j], acc[i][j], 0, 0, 0);
        }
    }

    // ---- epilogue: provisional spikes into LDS (pitch 132), borderline -> list ----
    __syncthreads();
    unsigned char* sp = (unsigned char*)smem;
#pragma unroll
    for (int i = 0; i < 4; ++i) {
#pragma unroll
        for (int j = 0; j < 4; ++j) {
            int cb = n0w + j * 16 + lm;          // col in block [0,128)
            int cg = by * 128 + cb;              // global col [0,768)
            float bj = bias[cg];
#pragma unroll
            for (int r = 0; r < 4; ++r) {
                int s = m0 + i * 16 + lq * 4 + r;
                float v = acc[i][j][r] + bj;
                if (fabsf(v - 2.0f) < 1e-4f) {
                    unsigned slot = atomicAdd(rcnt, 1u);
                    if (slot < RCAP)
                        rl[slot] = ((unsigned)mb << 17) | ((unsigned)s << 10) | (unsigned)cg;
                }
                sp[s * 132 + cb] = (v >= 2.0f) ? 1 : 0;
            }
        }
    }
    __syncthreads();

    if (by < 2) {
        int s = tid >> 1, half = tid & 1;
        const unsigned* spw = (const unsigned*)sp;
        unsigned o[16];
#pragma unroll
        for (int i2 = 0; i2 < 16; ++i2) o[i2] = spw[s * 33 + half * 16 + i2];
        uint4* dst = (uint4*)(q8 + (size_t)(mb * 128 + s) * 256 + by * 128 + half * 64);
#pragma unroll
        for (int q4 = 0; q4 < 4; ++q4) {
            uint4 t4; t4.x = o[q4*4+0]; t4.y = o[q4*4+1]; t4.z = o[q4*4+2]; t4.w = o[q4*4+3];
            dst[q4] = t4;
        }
    } else {
        int j = tid & 127, w2 = tid >> 7;
        unsigned m0w = 0, m1w = 0;
#pragma unroll
        for (int ii = 0; ii < 32; ++ii) {
            m0w |= (unsigned)(sp[(w2 * 64 + ii) * 132 + j] & 1) << ii;
            m1w |= (unsigned)(sp[(w2 * 64 + 32 + ii) * 132 + j] & 1) << ii;
        }
        int c = ((by - 2) & 1) * 128 + j;
        unsigned* dstb = ((by < 4) ? kb : vb) + ((size_t)mb * 256 + c) * 4 + w2 * 2;
        dstb[0] = m0w;
        dstb[1] = m1w;
    }
}

// ---- rescue: exact serial ascending-k fp32 FMA (replicates np sgemm rounding),
// patch q8 bytes / kb,vb bits. ~hundreds of entries, runs in a few µs. ----
__global__ __launch_bounds__(256) void rescue_fix(const float* __restrict__ x,
        const float* __restrict__ W, const float* __restrict__ bias,
        const unsigned* __restrict__ rl, const unsigned* __restrict__ rcnt,
        unsigned char* __restrict__ q8, unsigned* __restrict__ kb,
        unsigned* __restrict__ vb) {
    unsigned n = *rcnt; if (n > RCAP) n = RCAP;
    int wid = blockIdx.x * 4 + (threadIdx.x >> 6);
    int lane = threadIdx.x & 63;
    int nwv = gridDim.x * 4;
    for (unsigned e = wid; e < n; e += nwv) {
        unsigned ent = rl[e];
        int mb = ent >> 17, s = (ent >> 10) & 127, cg = ent & 1023;
        const float* ar = x + xoff_row(mb, s);
        const float* wc = W + cg;
        float da = 0.f;                     // all lanes redundantly (broadcast loads)
        for (int k = 0; k < 256; ++k)
            da = fmaf(ar[k], wc[(size_t)k * NC3], da);
        da += bias[cg];
        unsigned char spk = (da >= 2.0f) ? 1 : 0;
        if (lane == 0) {
            if (cg < 256) {
                q8[(size_t)(mb * 128 + s) * 256 + cg] = spk;
            } else {
                unsigned* tgt = (cg < 512) ? kb : vb;
                int c = cg & 255;
                unsigned* wp = tgt + ((size_t)mb * 256 + c) * 4 + (s >> 5);
                unsigned bit = 1u << (s & 31);
                unsigned cur = *wp;
                int have = (cur & bit) ? 1 : 0;
                if (have != (int)spk) atomicXor(wp, bit);
            }
        }
    }
}

// ---- K3.5: column sums of k spikes from bitmasks ----
__global__ __launch_bounds__(256) void kcs_bits(const unsigned* __restrict__ kb,
                                                float* __restrict__ kcs) {
    int g = blockIdx.x;
    int c = threadIdx.x;
    const unsigned* p = kb + ((size_t)g * 256 + c) * 4;
    int acc = __popc(p[0]) + __popc(p[1]) + __popc(p[2]) + __popc(p[3]);
    kcs[g * C_ + c] = (float)acc;
}

// ---- K4: kv[g,h,d,e] = popcount over gathered s-bitmasks (exact int) ----
__global__ __launch_bounds__(256) void kv_bits(const unsigned* __restrict__ kb,
        const unsigned* __restrict__ vb, const int* __restrict__ idx,
        float* __restrict__ kvbuf) {
    int g = blockIdx.x;            // 512
    int tb = g >> 6, n = g & 63, b = tb & 1;
    int tid = threadIdx.x;
    __shared__ uint4 kbl[1024];
    __shared__ uint4 vbl[1024];
    __shared__ int widx[TOPK_];
    if (tid < TOPK_) widx[tid] = idx[(b * 64 + n) * TOPK_ + tid];
    __syncthreads();
#pragma unroll
    for (int kk = 0; kk < TOPK_; ++kk) {
        int g2 = tb * 64 + widx[kk];
        kbl[kk * 256 + tid] = *(const uint4*)&kb[((size_t)g2 * 256 + tid) * 4];
        vbl[kk * 256 + tid] = *(const uint4*)&vb[((size_t)g2 * 256 + tid) * 4];
    }
    __syncthreads();
    int h = tid >> 5, e = tid & 31;
    uint4 vw0 = vbl[0 * 256 + h * 32 + e];
    uint4 vw1 = vbl[1 * 256 + h * 32 + e];
    uint4 vw2 = vbl[2 * 256 + h * 32 + e];
    uint4 vw3 = vbl[3 * 256 + h * 32 + e];
    for (int d = 0; d < 32; ++d) {
        uint4 k0 = kbl[0 * 256 + h * 32 + d];
        uint4 k1 = kbl[1 * 256 + h * 32 + d];
        uint4 k2 = kbl[2 * 256 + h * 32 + d];
        uint4 k3 = kbl[3 * 256 + h * 32 + d];
        int acc = __popc(k0.x & vw0.x) + __popc(k0.y & vw0.y)
                + __popc(k0.z & vw0.z) + __popc(k0.w & vw0.w)
                + __popc(k1.x & vw1.x) + __popc(k1.y & vw1.y)
                + __popc(k1.z & vw1.z) + __popc(k1.w & vw1.w)
                + __popc(k2.x & vw2.x) + __popc(k2.y & vw2.y)
                + __popc(k2.z & vw2.z) + __popc(k2.w & vw2.w)
                + __popc(k3.x & vw3.x) + __popc(k3.y & vw3.y)
                + __popc(k3.z & vw3.z) + __popc(k3.w & vw3.w);
        kvbuf[((size_t)(g * 8 + h) * 32 + d) * 32 + e] = (float)acc;
    }
}

__device__ __forceinline__ unsigned p4(unsigned xv) {
    return (xv & 1u) | ((xv >> 7) & 2u) | ((xv >> 14) & 4u) | ((xv >> 21) & 8u);
}

// ---- K5: attn -> swizzled bf16 hi/lo directly into A2p (proj GEMM input) ----
__global__ __launch_bounds__(256) void attn_kernel(const unsigned char* __restrict__ q8,
        const float* __restrict__ kvbuf, const float* __restrict__ kcs,
        const int* __restrict__ idx, short* __restrict__ A2p) {
    int g = blockIdx.x;            // 512
    int tb = g >> 6, n = g & 63, b = tb & 1;
    int tid = threadIdx.x;
    int h = tid >> 5, e = tid & 31;
    __shared__ unsigned qb[128 * 8];
    __shared__ float kslds[C_];
    __shared__ int widx[TOPK_];
    if (tid < TOPK_) widx[tid] = idx[(b * 64 + n) * TOPK_ + tid];
    __syncthreads();
    float ks = 0.f;
#pragma unroll
    for (int kk = 0; kk < TOPK_; ++kk)
        ks += kcs[(size_t)(tb * 64 + widx[kk]) * C_ + tid];
    kslds[tid] = ks;
    for (int w = tid; w < 1024; w += 256) {
        int s = w >> 3, hh = w & 7;
        const uint4* p = (const uint4*)(q8 + ((size_t)(g * 128 + s)) * 256 + hh * 32);
        uint4 lo = p[0], hi = p[1];
        unsigned m = p4(lo.x) | (p4(lo.y) << 4) | (p4(lo.z) << 8) | (p4(lo.w) << 12)
                   | (p4(hi.x) << 16) | (p4(hi.y) << 20) | (p4(hi.z) << 24) | (p4(hi.w) << 28);
        qb[w] = m;
    }
    __syncthreads();
    float kvr[32], ksr[32];
#pragma unroll
    for (int d = 0; d < 32; ++d)
        kvr[d] = kvbuf[((size_t)(g * 8 + h) * 32 + d) * 32 + e];
#pragma unroll
    for (int d = 0; d < 32; ++d) ksr[d] = kslds[h * 32 + d];
    for (int s = 0; s < 128; ++s) {
        unsigned qw = qb[s * 8 + h];
        float r;
        if (qw == 0u) {
            r = 0.f;
        } else {
            float num = 0.f, den = 0.f;
#pragma unroll
            for (int d = 0; d < 32; ++d) {
                float m = (float)((qw >> d) & 1u);
                num = fmaf(m, kvr[d], num);
                den = fmaf(m, ksr[d], den);
            }
            r = num / (den + 1e-6f);
        }
        short hi16 = f2bf(r);
        short lo16 = f2bf(r - bf2f(hi16));
        size_t row = (size_t)(g * 128 + s) * 512;
        A2p[row + swz(tid, s)] = hi16;
        A2p[row + swz(256 + tid, s)] = lo16;
    }
}

// ---- K6: proj GEMM via bf16x3 MFMA (BK=64) + bias + un-windowize store ----
__global__ __launch_bounds__(256) void proj_mfma(const short* __restrict__ A2p,
        const short* __restrict__ Bp, const float* __restrict__ bias,
        float* __restrict__ out) {
    __shared__ __align__(16) char smem[32768];
    short* At = (short*)smem;
    short* Bt = (short*)(smem + 16384);
    const int tid = threadIdx.x;
    const int mb = blockIdx.x;           // 512
    const int by = blockIdx.y;           // 2
    const int lr = tid >> 3, lc = (tid & 7) * 8;
    const short* Abase = A2p + (size_t)(mb * 128 + lr) * 512 + lc;
    const short* Bbase = Bp + (size_t)(by * 128 + lr) * 768 + lc;

    const int wv = tid >> 6, lane = tid & 63;
    const int m0 = (wv >> 1) * 64, n0w = (wv & 1) * 64;
    const int lm = lane & 15, lq = lane >> 4;
    const int sx = lm & 7;

    floatx4 acc[4][4];
#pragma unroll
    for (int i = 0; i < 4; ++i)
#pragma unroll
        for (int j = 0; j < 4; ++j) acc[i][j] = (floatx4)0.f;

    for (int kt = 0; kt < 768; kt += 64) {
        int ca = (kt < 512) ? kt : kt - 512;
        __syncthreads();
#pragma unroll
        for (int c = 0; c < 4; ++c) {
            gload16(Abase + ca + (size_t)c * 32 * 512, At + c * 2048 + tid * 8);
            gload16(Bbase + kt + (size_t)c * 32 * 768, Bt + c * 2048 + tid * 8);
        }
        __syncthreads();
#pragma unroll
        for (int kq = 0; kq < 2; ++kq) {
            short8 af[4], bfv[4];
            const int ko = ((kq * 4 + lq) ^ sx) * 8;
#pragma unroll
            for (int i = 0; i < 4; ++i)
                af[i] = *(const short8*)&At[(m0 + i * 16 + lm) * 64 + ko];
#pragma unroll
            for (int j = 0; j < 4; ++j)
                bfv[j] = *(const short8*)&Bt[(n0w + j * 16 + lm) * 64 + ko];
#pragma unroll
            for (int i = 0; i < 4; ++i)
#pragma unroll
                for (int j = 0; j < 4; ++j)
                    acc[i][j] = __builtin_amdgcn_mfma_f32_16x16x32_bf16(
                        af[i], bfv[j], acc[i][j], 0, 0, 0);
        }
    }

#pragma unroll
    for (int i = 0; i < 4; ++i) {
#pragma unroll
        for (int j = 0; j < 4; ++j) {
            int c = by * 128 + n0w + j * 16 + lm;
            float bj = bias[c];
#pragma unroll
            for (int r = 0; r < 4; ++r) {
                int s = m0 + i * 16 + lq * 4 + r;
                out[xoff_row(mb, s) + c] = acc[i][j][r] + bj;
            }
        }
    }
}

extern "C" void kernel_launch(void* const* d_in, const int* in_sizes, int n_in,
                              void* d_out, int out_size, void* d_ws, size_t ws_size,
                              hipStream_t stream) {
    (void)in_sizes; (void)n_in; (void)out_size; (void)ws_size;
    const float* x    = (const float*)d_in[0];
    const float* Wqkv = (const float*)d_in[1];
    const float* bqkv = (const float*)d_in[2];
    const float* Wp   = (const float*)d_in[3];
    const float* bp   = (const float*)d_in[4];
    char* ws = (char*)d_ws;
    short*    A2    = (short*)   (ws + OFF_A2);
    short*    Bq    = (short*)   (ws + OFF_BQ);
    short*    Bpj   = (short*)   (ws + OFF_BP);
    unsigned char* q8 = (unsigned char*)(ws + OFF_Q8);
    unsigned* kb    = (unsigned*)(ws + OFF_KB);
    unsigned* vb    = (unsigned*)(ws + OFF_VB);
    float*    kvbuf = (float*)   (ws + OFF_KV);
    float*    kcs   = (float*)   (ws + OFF_KCS);
    float*    part  = (float*)   (ws + OFF_PART);
    float*    region= (float*)   (ws + OFF_REGION);
    int*      idxb  = (int*)     (ws + OFF_IDX);
    unsigned* rl    = (unsigned*)(ws + OFF_RL);
    unsigned* rcnt  = (unsigned*)(ws + OFF_RC);
    float*    out   = (float*)d_out;

    hipMemsetAsync(rcnt, 0, 4, stream);
    b_build_qkv    <<<dim3(768, 3), 256, 0, stream>>>(Wqkv, Bq);
    b_build_proj   <<<768, 256, 0, stream>>>(Wp, Bpj);
    k_partial_split<<<512, 256, 0, stream>>>(x, part, A2);
    k_region       <<<128, 256, 0, stream>>>(part, region);
    k_scores       <<<128,  64, 0, stream>>>(region, idxb);
    qkv_mfma       <<<dim3(512, 6), 256, 0, stream>>>(A2, Bq, bqkv, q8, kb, vb, rl, rcnt);
    rescue_fix     <<<128, 256, 0, stream>>>(x, Wqkv, bqkv, rl, rcnt, q8, kb, vb);
    kcs_bits       <<<512, 256, 0, stream>>>(kb, kcs);
    kv_bits        <<<512, 256, 0, stream>>>(kb, vb, idxb, kvbuf);
    attn_kernel    <<<512, 256, 0, stream>>>(q8, kvbuf, kcs, idxb, A2);
    proj_mfma      <<<dim3(512, 2), 256, 0, stream>>>(A2, Bpj, bp, out);
}

// Round 5
// 410.041 us; speedup vs baseline: 1.6824x; 1.0984x over previous
//
#include <hip/hip_runtime.h>
#include <cstdint>
#include <cstddef>

// Problem constants (fixed by reference shapes)
#define T_    4
#define B_    2
#define NW_   64
#define WS_   128
#define C_    256
#define NC3   768
#define H_    8
#define HD_   32
#define TOPK_ 4
#define RCAP  65536

// Workspace layout (bytes, all 16B aligned). Total ~93.2 MB.
// A2/Bq/Bp are stored FRAGMENT-MAJOR: the exact 16x16x32-bf16 MFMA operand
// register layout (lane = (m|n)&15 | octet<<4, 8 contiguous shorts per lane),
// so GEMM kernels load operands straight into VGPRs -> no LDS, no K-loop
// barriers (the m97 barrier-drain killer).
#define OFF_A2     0ull            // [mb][gi 0..7][ktA 0..15][lane][8] = 64 MB
#define OFF_BQ     67108864ull     // [gj 0..47][ktB 0..23][lane][8] = 1,179,648
#define OFF_BP     68288512ull     // [gj 0..15][ktB 0..23][lane][8] = 393,216
#define OFF_QM     68681728ull     // qmask u32 [g][s][h] = 2,097,152
#define OFF_KB     70778880ull     // 2,097,152
#define OFF_VB     72876032ull     // 2,097,152
#define OFF_KV     74973184ull     // 16,777,216
#define OFF_KCS    91750400ull     // 524,288
#define OFF_PART   92274688ull     // 524,288
#define OFF_REGION 92798976ull     // 131,072
#define OFF_IDX    92930048ull     // 2,048
#define OFF_RL     92932096ull     // 262,144
#define OFF_RC     93194240ull     // 16

typedef short short8 __attribute__((ext_vector_type(8)));
typedef float floatx4 __attribute__((ext_vector_type(4)));

__device__ __forceinline__ short f2bf(float f) {
    unsigned u = __float_as_uint(f);
    unsigned r = (u + 0x7fffu + ((u >> 16) & 1u)) >> 16;
    return (short)r;
}
__device__ __forceinline__ float bf2f(short h) {
    return __uint_as_float(((unsigned)(unsigned short)h) << 16);
}

// g = (t*B_+b)*NW_ + n, s in [0,128): float index of x[t,b,lt,lh,lw,0]
__device__ __forceinline__ int xoff_row(int g, int s) {
    int tb = g >> 6;
    int n  = g & 63;
    int iwt = n >> 4, iwh = (n >> 2) & 3, iww = n & 3;
    int ipt = s >> 6, iph = (s >> 3) & 7, ipw = s & 7;
    int lt = iwt * 2 + ipt, lh = iwh * 8 + iph, lw = iww * 8 + ipw;
    return (((tb * 8 + lt) * 32 + lh) * 32 + lw) * 256;
}

// ---- K1a: partial sums + write A2 in fragment-major bf16 hi/lo ----
__global__ __launch_bounds__(256) void k_partial_split(const float* __restrict__ x,
        float* __restrict__ part, short* __restrict__ A2) {
    int g = blockIdx.x;            // 512
    int c = threadIdx.x;
    const int ktAh = c >> 5, ktAl = 8 + (c >> 5);
    const int octsh = ((c >> 3) & 3) << 4, sub = c & 7;
    float acc = 0.f;
    for (int s = 0; s < WS_; ++s) {
        float v = x[xoff_row(g, s) + c];
        acc += v;
        short hi = f2bf(v);
        short lo = f2bf(v - bf2f(hi));
        int lane = (s & 15) | octsh;
        size_t base = ((size_t)(g * 8 + (s >> 4))) * 16;
        A2[(base + ktAh) * 512 + lane * 8 + sub] = hi;
        A2[(base + ktAl) * 512 + lane * 8 + sub] = lo;
    }
    part[g * C_ + c] = acc;
}

// ---- K1b: region[b,n,c] = sum_t part / 128 ----
__global__ __launch_bounds__(256) void k_region(const float* __restrict__ part,
                                                float* __restrict__ region) {
    int bn = blockIdx.x;           // 128
    int c = threadIdx.x;
    int b = bn >> 6, n = bn & 63;
    float acc = 0.f;
    for (int t = 0; t < T_; ++t) acc += part[((t * 2 + b) * 64 + n) * C_ + c];
    region[bn * C_ + c] = acc * (1.0f / 128.0f);
}

// ---- K2: scores + top-4 (lowest-index tie-break) ----
__global__ __launch_bounds__(64) void k_scores(const float* __restrict__ region,
                                               int* __restrict__ idx) {
    int bi = blockIdx.x;           // 128
    int b = bi >> 6, i = bi & 63;
    int tid = threadIdx.x;
    __shared__ float ri[C_];
    __shared__ float sc[64];
    for (int c = tid; c < C_; c += 64) ri[c] = region[(b * 64 + i) * C_ + c];
    __syncthreads();
    const float* rj = region + (size_t)(b * 64 + tid) * C_;
    float dot = 0.f;
    for (int c = 0; c < C_; ++c) dot += ri[c] * rj[c];
    sc[tid] = dot * 0.17677669529663687f;
    __syncthreads();
    if (tid == 0) {
        for (int kk = 0; kk < TOPK_; ++kk) {
            float best = -INFINITY; int bj = 0;
            for (int j = 0; j < 64; ++j)
                if (sc[j] > best) { best = sc[j]; bj = j; }
            idx[bi * TOPK_ + kk] = bj;
            sc[bj] = -INFINITY;
        }
    }
}

// ---- B' builders, fragment-major; k' = [hi(W) | hi(W) | lo(W)] ----
__global__ __launch_bounds__(256) void b_build_qkv(const float* __restrict__ W,
                                                   short* __restrict__ Bq) {
    int ke = blockIdx.x;                     // 0..767
    int n = blockIdx.y * 256 + threadIdx.x;  // 0..767
    float wv = W[(size_t)(ke & 255) * NC3 + n];
    short hi = f2bf(wv);
    short o = (ke < 512) ? hi : f2bf(wv - bf2f(hi));
    int gj = n >> 4, lmn = n & 15, ktB = ke >> 5, oct = (ke >> 3) & 3, sub = ke & 7;
    Bq[(size_t)((gj * 24 + ktB) * 64 + (lmn | (oct << 4))) * 8 + sub] = o;
}
__global__ __launch_bounds__(256) void b_build_proj(const float* __restrict__ W,
                                                    short* __restrict__ Bp) {
    int ke = blockIdx.x;                // 0..767
    int n = threadIdx.x;                // 0..255
    float wv = W[(size_t)(ke & 255) * 256 + n];
    short hi = f2bf(wv);
    short o = (ke < 512) ? hi : f2bf(wv - bf2f(hi));
    int gj = n >> 4, lmn = n & 15, ktB = ke >> 5, oct = (ke >> 3) & 3, sub = ke & 7;
    Bp[(size_t)((gj * 24 + ktB) * 64 + (lmn | (oct << 4))) * 8 + sub] = o;
}

__device__ __forceinline__ unsigned p4(unsigned xv) {
    return (xv & 1u) | ((xv >> 7) & 2u) | ((xv >> 14) & 4u) | ((xv >> 21) & 8u);
}

// ---- K3: qkv GEMM, fragment-direct (NO LDS in K-loop, NO barriers).
// grid (512, 3): p=0 -> q masks, p=1 -> k bits, p=2 -> v bits (N=256 each).
__global__ __launch_bounds__(256, 2) void qkv_mfma(const short* __restrict__ A2,
        const short* __restrict__ Bq, const float* __restrict__ bias,
        unsigned* __restrict__ qm, unsigned* __restrict__ kb,
        unsigned* __restrict__ vb, unsigned* __restrict__ rl,
        unsigned* __restrict__ rcnt) {
    __shared__ unsigned char sp[128 * 264];
    const int tid = threadIdx.x, mb = blockIdx.x, p = blockIdx.y;
    const int wv = tid >> 6, lane = tid & 63;
    const int wm = wv >> 1, wn = wv & 1;
    const int lm = lane & 15, lq = lane >> 4;

    floatx4 acc[4][8];
#pragma unroll
    for (int i = 0; i < 4; ++i)
#pragma unroll
        for (int j = 0; j < 8; ++j) acc[i][j] = (floatx4)0.f;

    const short* Ab = A2 + ((size_t)(mb * 8 + wm * 4) * 16) * 512 + lane * 8;
    const short* Bb = Bq + ((size_t)(p * 16 + wn * 8) * 24) * 512 + lane * 8;

#pragma unroll 2
    for (int kt = 0; kt < 24; ++kt) {
        int ktA = (kt < 16) ? kt : kt - 16;
        short8 af[4], bf[8];
#pragma unroll
        for (int i = 0; i < 4; ++i)
            af[i] = *(const short8*)(Ab + (size_t)(i * 16 + ktA) * 512);
#pragma unroll
        for (int j = 0; j < 8; ++j)
            bf[j] = *(const short8*)(Bb + (size_t)(j * 24 + kt) * 512);
#pragma unroll
        for (int i = 0; i < 4; ++i)
#pragma unroll
            for (int j = 0; j < 8; ++j)
                acc[i][j] = __builtin_amdgcn_mfma_f32_16x16x32_bf16(
                    af[i], bf[j], acc[i][j], 0, 0, 0);
    }

    // epilogue: spikes into LDS; borderline -> rescue list
#pragma unroll
    for (int i = 0; i < 4; ++i) {
#pragma unroll
        for (int j = 0; j < 8; ++j) {
            int cb = wn * 128 + j * 16 + lm;
            int cg = p * 256 + cb;
            float bj = bias[cg];
#pragma unroll
            for (int r = 0; r < 4; ++r) {
                int s = wm * 64 + i * 16 + lq * 4 + r;
                float v = acc[i][j][r] + bj;
                if (fabsf(v - 2.0f) < 1e-4f) {
                    unsigned slot = atomicAdd(rcnt, 1u);
                    if (slot < RCAP)
                        rl[slot] = ((unsigned)mb << 17) | ((unsigned)s << 10) | (unsigned)cg;
                }
                sp[s * 264 + cb] = (v >= 2.0f) ? 1 : 0;
            }
        }
    }
    __syncthreads();

    if (p == 0) {
        // pack q bitmasks over channel-within-head: qm[g][s][h]
        const unsigned* spw = (const unsigned*)sp;   // pitch 66 words
#pragma unroll
        for (int t = 0; t < 4; ++t) {
            int w = t * 256 + tid;
            int s = w >> 3, h = w & 7;
            unsigned m = 0;
#pragma unroll
            for (int q = 0; q < 8; ++q)
                m |= p4(spw[s * 66 + h * 8 + q]) << (q * 4);
            qm[(size_t)mb * 1024 + w] = m;
        }
    } else {
        // pack k/v bitmasks along s: (kb|vb)[(mb*256+c)*4 + w2]
        unsigned wrd[4];
#pragma unroll
        for (int w2 = 0; w2 < 4; ++w2) {
            unsigned m = 0;
#pragma unroll
            for (int ii = 0; ii < 32; ++ii)
                m |= (unsigned)(sp[(w2 * 32 + ii) * 264 + tid] & 1) << ii;
            wrd[w2] = m;
        }
        uint4 o; o.x = wrd[0]; o.y = wrd[1]; o.z = wrd[2]; o.w = wrd[3];
        *(uint4*)(((p == 1) ? kb : vb) + ((size_t)mb * 256 + tid) * 4) = o;
    }
}

// ---- rescue: serial ascending-k fp32 FMA (replicates np sgemm rounding) ----
__global__ __launch_bounds__(256) void rescue_fix(const float* __restrict__ x,
        const float* __restrict__ W, const float* __restrict__ bias,
        const unsigned* __restrict__ rl, const unsigned* __restrict__ rcnt,
        unsigned* __restrict__ qm, unsigned* __restrict__ kb,
        unsigned* __restrict__ vb) {
    unsigned n = *rcnt; if (n > RCAP) n = RCAP;
    int wid = blockIdx.x * 4 + (threadIdx.x >> 6);
    int lane = threadIdx.x & 63;
    int nwv = gridDim.x * 4;
    for (unsigned e = wid; e < n; e += nwv) {
        unsigned ent = rl[e];
        int mb = ent >> 17, s = (ent >> 10) & 127, cg = ent & 1023;
        const float* ar = x + xoff_row(mb, s);
        const float* wc = W + cg;
        float da = 0.f;
        for (int k = 0; k < 256; ++k)
            da = fmaf(ar[k], wc[(size_t)k * NC3], da);
        da += bias[cg];
        int spk = (da >= 2.0f) ? 1 : 0;
        if (lane == 0) {
            if (cg < 256) {
                int h = cg >> 5, d = cg & 31;
                unsigned* wp = qm + (size_t)mb * 1024 + s * 8 + h;
                unsigned bit = 1u << d;
                int have = (*wp & bit) ? 1 : 0;
                if (have != spk) atomicXor(wp, bit);
            } else {
                unsigned* tgt = (cg < 512) ? kb : vb;
                int c = cg & 255;
                unsigned* wp = tgt + ((size_t)mb * 256 + c) * 4 + (s >> 5);
                unsigned bit = 1u << (s & 31);
                int have = (*wp & bit) ? 1 : 0;
                if (have != spk) atomicXor(wp, bit);
            }
        }
    }
}

// ---- K3.5: column sums of k spikes from bitmasks ----
__global__ __launch_bounds__(256) void kcs_bits(const unsigned* __restrict__ kb,
                                                float* __restrict__ kcs) {
    int g = blockIdx.x;
    int c = threadIdx.x;
    const unsigned* p = kb + ((size_t)g * 256 + c) * 4;
    int acc = __popc(p[0]) + __popc(p[1]) + __popc(p[2]) + __popc(p[3]);
    kcs[g * C_ + c] = (float)acc;
}

// ---- K4: kv[g,h,d,e] = popcount over gathered s-bitmasks (exact int) ----
__global__ __launch_bounds__(256) void kv_bits(const unsigned* __restrict__ kb,
        const unsigned* __restrict__ vb, const int* __restrict__ idx,
        float* __restrict__ kvbuf) {
    int g = blockIdx.x;            // 512
    int tb = g >> 6, n = g & 63, b = tb & 1;
    int tid = threadIdx.x;
    __shared__ uint4 kbl[1024];
    __shared__ uint4 vbl[1024];
    __shared__ int widx[TOPK_];
    if (tid < TOPK_) widx[tid] = idx[(b * 64 + n) * TOPK_ + tid];
    __syncthreads();
#pragma unroll
    for (int kk = 0; kk < TOPK_; ++kk) {
        int g2 = tb * 64 + widx[kk];
        kbl[kk * 256 + tid] = *(const uint4*)&kb[((size_t)g2 * 256 + tid) * 4];
        vbl[kk * 256 + tid] = *(const uint4*)&vb[((size_t)g2 * 256 + tid) * 4];
    }
    __syncthreads();
    int h = tid >> 5, e = tid & 31;
    uint4 vw0 = vbl[0 * 256 + h * 32 + e];
    uint4 vw1 = vbl[1 * 256 + h * 32 + e];
    uint4 vw2 = vbl[2 * 256 + h * 32 + e];
    uint4 vw3 = vbl[3 * 256 + h * 32 + e];
    for (int d = 0; d < 32; ++d) {
        uint4 k0 = kbl[0 * 256 + h * 32 + d];
        uint4 k1 = kbl[1 * 256 + h * 32 + d];
        uint4 k2 = kbl[2 * 256 + h * 32 + d];
        uint4 k3 = kbl[3 * 256 + h * 32 + d];
        int acc = __popc(k0.x & vw0.x) + __popc(k0.y & vw0.y)
                + __popc(k0.z & vw0.z) + __popc(k0.w & vw0.w)
                + __popc(k1.x & vw1.x) + __popc(k1.y & vw1.y)
                + __popc(k1.z & vw1.z) + __popc(k1.w & vw1.w)
                + __popc(k2.x & vw2.x) + __popc(k2.y & vw2.y)
                + __popc(k2.z & vw2.z) + __popc(k2.w & vw2.w)
                + __popc(k3.x & vw3.x) + __popc(k3.y & vw3.y)
                + __popc(k3.z & vw3.z) + __popc(k3.w & vw3.w);
        kvbuf[((size_t)(g * 8 + h) * 32 + d) * 32 + e] = (float)acc;
    }
}

// ---- K5: FUSED attn + proj. One block = 32 rows of one window g.
// attn result split hi/lo -> LDS fragment-major -> proj MFMA with frag-major
// Bp from L2 -> bias -> LDS row-stage -> coalesced un-windowize store.
__global__ __launch_bounds__(256) void attn_proj(const unsigned* __restrict__ qm,
        const float* __restrict__ kvbuf, const float* __restrict__ kcs,
        const int* __restrict__ idx, const short* __restrict__ Bp,
        const float* __restrict__ bias, float* __restrict__ out) {
    __shared__ __align__(16) short aw[16384];   // 32 KB frags; reused as float ow[32][256]
    __shared__ unsigned qb[256];
    __shared__ float ksl[256];
    __shared__ int widx[TOPK_];
    const int bid = blockIdx.x;        // 2048
    const int g = bid >> 2, qr = bid & 3;
    const int tb = g >> 6, n = g & 63, b = tb & 1;
    const int tid = threadIdx.x;
    if (tid < TOPK_) widx[tid] = idx[(b * 64 + n) * TOPK_ + tid];
    __syncthreads();
    float ks = 0.f;
#pragma unroll
    for (int kk = 0; kk < TOPK_; ++kk)
        ks += kcs[(size_t)(tb * 64 + widx[kk]) * C_ + tid];
    ksl[tid] = ks;
    qb[tid] = qm[(size_t)g * 1024 + qr * 256 + tid];
    __syncthreads();

    const int h = tid >> 5, e = tid & 31;
    float kvr[32], ksr[32];
#pragma unroll
    for (int d = 0; d < 32; ++d)
        kvr[d] = kvbuf[((size_t)(g * 8 + h) * 32 + d) * 32 + e];
#pragma unroll
    for (int d = 0; d < 32; ++d) ksr[d] = ksl[h * 32 + d];

    const int ktAh = tid >> 5, ktAl = 8 + (tid >> 5);
    const int octsh = ((tid >> 3) & 3) << 4, sub = tid & 7;
    for (int sl = 0; sl < 32; ++sl) {
        unsigned qw = qb[sl * 8 + h];
        float r;
        if (qw == 0u) {
            r = 0.f;
        } else {
            float num = 0.f, den = 0.f;
#pragma unroll
            for (int d = 0; d < 32; ++d) {
                float m = (float)((qw >> d) & 1u);
                num = fmaf(m, kvr[d], num);
                den = fmaf(m, ksr[d], den);
            }
            r = num / (den + 1e-6f);
        }
        short hi = f2bf(r), lo = f2bf(r - bf2f(hi));
        int lane2 = (sl & 15) | octsh;
        int gi = sl >> 4;
        aw[((gi * 16 + ktAh) * 64 + lane2) * 8 + sub] = hi;
        aw[((gi * 16 + ktAl) * 64 + lane2) * 8 + sub] = lo;
    }
    __syncthreads();

    // proj: M=32, N=256; 4 waves each N=64
    const int wvw = tid >> 6, lane = tid & 63;
    const int lm = lane & 15, lq = lane >> 4;
    floatx4 pacc[2][4];
#pragma unroll
    for (int i = 0; i < 2; ++i)
#pragma unroll
        for (int j = 0; j < 4; ++j) pacc[i][j] = (floatx4)0.f;
    const short* Bb = Bp + ((size_t)(wvw * 4) * 24) * 512 + lane * 8;
#pragma unroll 2
    for (int kt = 0; kt < 24; ++kt) {
        int ktA = (kt < 16) ? kt : kt - 16;
        short8 af[2], bf[4];
#pragma unroll
        for (int i = 0; i < 2; ++i)
            af[i] = *(const short8*)&aw[((i * 16 + ktA) * 64 + lane) * 8];
#pragma unroll
        for (int j = 0; j < 4; ++j)
            bf[j] = *(const short8*)(Bb + (size_t)(j * 24 + kt) * 512);
#pragma unroll
        for (int i = 0; i < 2; ++i)
#pragma unroll
            for (int j = 0; j < 4; ++j)
                pacc[i][j] = __builtin_amdgcn_mfma_f32_16x16x32_bf16(
                    af[i], bf[j], pacc[i][j], 0, 0, 0);
    }
    __syncthreads();

    float* ow = (float*)aw;            // 32 x 256 fp32 rows
#pragma unroll
    for (int i = 0; i < 2; ++i) {
#pragma unroll
        for (int j = 0; j < 4; ++j) {
            int c = wvw * 64 + j * 16 + lm;
            float bj = bias[c];
#pragma unroll
            for (int r = 0; r < 4; ++r)
                ow[(i * 16 + lq * 4 + r) * 256 + c] = pacc[i][j][r] + bj;
        }
    }
    __syncthreads();

    // coalesced un-windowize store: rows are contiguous 1 KB in out
    int sl2 = tid >> 3, pc = (tid & 7) * 32;
    int off = xoff_row(g, qr * 32 + sl2) + pc;
#pragma unroll
    for (int q = 0; q < 8; ++q)
        *(float4*)(out + off + q * 4) = *(const float4*)&ow[sl2 * 256 + pc + q * 4];
}

extern "C" void kernel_launch(void* const* d_in, const int* in_sizes, int n_in,
                              void* d_out, int out_size, void* d_ws, size_t ws_size,
                              hipStream_t stream) {
    (void)in_sizes; (void)n_in; (void)out_size; (void)ws_size;
    const float* x    = (const float*)d_in[0];
    const float* Wqkv = (const float*)d_in[1];
    const float* bqkv = (const float*)d_in[2];
    const float* Wp   = (const float*)d_in[3];
    const float* bp   = (const float*)d_in[4];
    char* ws = (char*)d_ws;
    short*    A2    = (short*)   (ws + OFF_A2);
    short*    Bq    = (short*)   (ws + OFF_BQ);
    short*    Bpj   = (short*)   (ws + OFF_BP);
    unsigned* qmv   = (unsigned*)(ws + OFF_QM);
    unsigned* kb    = (unsigned*)(ws + OFF_KB);
    unsigned* vb    = (unsigned*)(ws + OFF_VB);
    float*    kvbuf = (float*)   (ws + OFF_KV);
    float*    kcs   = (float*)   (ws + OFF_KCS);
    float*    part  = (float*)   (ws + OFF_PART);
    float*    region= (float*)   (ws + OFF_REGION);
    int*      idxb  = (int*)     (ws + OFF_IDX);
    unsigned* rl    = (unsigned*)(ws + OFF_RL);
    unsigned* rcnt  = (unsigned*)(ws + OFF_RC);
    float*    out   = (float*)d_out;

    hipMemsetAsync(rcnt, 0, 4, stream);
    b_build_qkv    <<<dim3(768, 3), 256, 0, stream>>>(Wqkv, Bq);
    b_build_proj   <<<768, 256, 0, stream>>>(Wp, Bpj);
    k_partial_split<<<512, 256, 0, stream>>>(x, part, A2);
    k_region       <<<128, 256, 0, stream>>>(part, region);
    k_scores       <<<128,  64, 0, stream>>>(region, idxb);
    qkv_mfma       <<<dim3(512, 3), 256, 0, stream>>>(A2, Bq, bqkv, qmv, kb, vb, rl, rcnt);
    rescue_fix     <<<128, 256, 0, stream>>>(x, Wqkv, bqkv, rl, rcnt, qmv, kb, vb);
    kcs_bits       <<<512, 256, 0, stream>>>(kb, kcs);
    kv_bits        <<<512, 256, 0, stream>>>(kb, vb, idxb, kvbuf);
    attn_proj      <<<2048, 256, 0, stream>>>(qmv, kvbuf, kcs, idxb, Bpj, bp, out);
}